// Round 15
// baseline (487.972 us; speedup 1.0000x reference)
//
#include <hip/hip_runtime.h>

#define DEVINL __device__ __forceinline__

#if __has_builtin(__builtin_amdgcn_exp2f)
DEVINL float fexp2(float x) { return __builtin_amdgcn_exp2f(x); }
#else
DEVINL float fexp2(float x) { return exp2f(x); }
#endif

// Sum over the 4 channel-quad lanes of a head (lane^1, lane^2) via ds_swizzle
// XOR immediates (BitMode: offset = (xor<<10) | 0x1F).
DEVINL float red4(float pv) {
    pv += __int_as_float(__builtin_amdgcn_ds_swizzle(__float_as_int(pv), 0x041F));
    pv += __int_as_float(__builtin_amdgcn_ds_swizzle(__float_as_int(pv), 0x081F));
    return pv;
}

// LDS-tiled GEMM: out[n, 0:128] = x[n, 0:K] @ [Wa | Wb].
template <int K>
__global__ void k_lin_tiled(const float* __restrict__ x,
                            const float* __restrict__ Wa,
                            const float* __restrict__ Wb,
                            float* __restrict__ oa, float* __restrict__ ob,
                            int N) {
    __shared__ float sx[64 * K];
    __shared__ float sw[K * 128];
    int t = threadIdx.x;
    int base = blockIdx.x * 64;

    const int WTOT = K * 64 / 4;
    for (int i = t; i < WTOT; i += 256) {
        float4 wa = ((const float4*)Wa)[i];
        float4 wb = ((const float4*)Wb)[i];
        int k = (i * 4) >> 6, f = (i * 4) & 63;
        *(float4*)&sw[k * 128 + f] = wa;
        *(float4*)&sw[k * 128 + 64 + f] = wb;
    }
    const int XTOT = 64 * K / 4;
    for (int i = t; i < XTOT; i += 256) {
        int n = (i * 4) / K, kk = (i * 4) % K;
        float4 v = make_float4(0.f, 0.f, 0.f, 0.f);
        if (base + n < N) v = *(const float4*)&x[(size_t)(base + n) * K + kk];
        *(float4*)&sx[n * K + kk] = v;
    }
    __syncthreads();

    int fq = t & 31;
    int nq = t >> 5;
    float acc[8][4];
#pragma unroll
    for (int i = 0; i < 8; ++i)
#pragma unroll
        for (int c = 0; c < 4; ++c) acc[i][c] = 0.f;

    for (int k0 = 0; k0 < K; k0 += 4) {
        float4 xv[8];
#pragma unroll
        for (int i = 0; i < 8; ++i)
            xv[i] = *(const float4*)&sx[(nq * 8 + i) * K + k0];
#pragma unroll
        for (int kk = 0; kk < 4; ++kk) {
            float4 w = *(const float4*)&sw[(k0 + kk) * 128 + fq * 4];
#pragma unroll
            for (int i = 0; i < 8; ++i) {
                float xs = (kk == 0) ? xv[i].x : (kk == 1) ? xv[i].y
                         : (kk == 2) ? xv[i].z : xv[i].w;
                acc[i][0] = fmaf(xs, w.x, acc[i][0]);
                acc[i][1] = fmaf(xs, w.y, acc[i][1]);
                acc[i][2] = fmaf(xs, w.z, acc[i][2]);
                acc[i][3] = fmaf(xs, w.w, acc[i][3]);
            }
        }
    }

    int col = fq * 4;
    float* o = (col < 64) ? oa : ob;
    int c = col & 63;
#pragma unroll
    for (int i = 0; i < 8; ++i) {
        int n = base + nq * 8 + i;
        if (n < N)
            *(float4*)&o[(size_t)n * 64 + c] =
                make_float4(acc[i][0], acc[i][1], acc[i][2], acc[i][3]);
    }
}

// ---- CSR build ----
__global__ void k_deg(const int* __restrict__ dst, int* __restrict__ deg, int E) {
    int e = blockIdx.x * blockDim.x + threadIdx.x;
    if (e < E) atomicAdd(&deg[dst[e]], 1);
}

__global__ void k_scan1(const int* __restrict__ deg, int* __restrict__ spart,
                        int* __restrict__ bsum, int N) {
    __shared__ int sh[256];
    int base = blockIdx.x * 1024;
    int t = threadIdx.x;
    int v[4]; int sum = 0;
#pragma unroll
    for (int i = 0; i < 4; ++i) {
        int idx = base + t * 4 + i;
        v[i] = (idx < N) ? deg[idx] : 0;
        sum += v[i];
    }
    sh[t] = sum;
    __syncthreads();
    for (int off = 1; off < 256; off <<= 1) {
        int x = (t >= off) ? sh[t - off] : 0;
        __syncthreads();
        sh[t] += x;
        __syncthreads();
    }
    int run = (t > 0) ? sh[t - 1] : 0;
#pragma unroll
    for (int i = 0; i < 4; ++i) {
        run += v[i];
        int idx = base + t * 4 + i;
        if (idx < N) spart[idx] = run;
    }
    if (t == 255) bsum[blockIdx.x] = sh[255];
}

__global__ void k_scan2(int* __restrict__ bsum, int nb) {
    __shared__ int sh[128];
    int t = threadIdx.x;
    sh[t] = (t < nb) ? bsum[t] : 0;
    __syncthreads();
    for (int off = 1; off < 128; off <<= 1) {
        int x = (t >= off) ? sh[t - off] : 0;
        __syncthreads();
        sh[t] += x;
        __syncthreads();
    }
    if (t < nb) bsum[t] = (t > 0) ? sh[t - 1] : 0;
}

__global__ void k_scan3(const int* __restrict__ spart, const int* __restrict__ bsum,
                        int* __restrict__ rowptr, int N) {
    int i = blockIdx.x * blockDim.x + threadIdx.x;
    if (i < N) rowptr[i + 1] = spart[i] + bsum[i >> 10];
    if (i == 0) rowptr[0] = 0;
}

// bucket fill init: bfill[b] = rowptr[min(b<<shift, N)]
__global__ void k_binit(const int* __restrict__ rowptr, int* __restrict__ bfill,
                        int shift, int B, int N) {
    int b = blockIdx.x * blockDim.x + threadIdx.x;
    if (b < B) {
        long long node = (long long)b << shift;
        if (node > N) node = N;
        bfill[b] = rowptr[node];
    }
}

// Pass A: partition edges into dst-range buckets (bucket = dst>>shift).
// 8B staging record: {eid:24 | src:28 | dst_low:12}. Writes are per-bucket
// contiguous runs (~8 records = 1 line) -> near-sequential.
__global__ void k_part(const int* __restrict__ src, const int* __restrict__ dst,
                       int* __restrict__ bfill, unsigned long long* __restrict__ stg,
                       int shift, int E, int chunk) {
    __shared__ int hist[512];
    __shared__ int base[512];
    int t = threadIdx.x;
    int e0 = blockIdx.x * chunk;
    int e1 = e0 + chunk; if (e1 > E) e1 = E;
    for (int i = t; i < 512; i += 256) hist[i] = 0;
    __syncthreads();
    for (int e = e0 + t; e < e1; e += 256)
        atomicAdd(&hist[(unsigned)dst[e] >> shift], 1);
    __syncthreads();
    for (int i = t; i < 512; i += 256) {
        int h = hist[i];
        base[i] = h ? atomicAdd(&bfill[i], h) : 0;
    }
    __syncthreads();
    for (int i = t; i < 512; i += 256) hist[i] = 0;
    __syncthreads();
    unsigned mask = (1u << shift) - 1u;
    for (int e = e0 + t; e < e1; e += 256) {
        int d = dst[e];
        int b = (unsigned)d >> shift;
        int off = atomicAdd(&hist[b], 1);
        unsigned long long p = ((unsigned long long)(unsigned)e << 40)
                             | ((unsigned long long)(unsigned)src[e] << 12)
                             | (unsigned long long)((unsigned)d & mask);
        stg[(size_t)(base[b] + off)] = p;
    }
}

// Pass B: one block per bucket; scatter within the bucket's contiguous CSR
// range -> all of a line's writes come from ONE block/CU/L2. Also permutes
// edge_attr into CSR order (random READ of ea, local write) so both agg
// layers stream it sequentially.
__global__ void k_scat2(const unsigned long long* __restrict__ stg,
                        const float4* __restrict__ ea,
                        const int* __restrict__ rowptr, int* __restrict__ fill,
                        float4* __restrict__ csr_ea, int* __restrict__ csr_src,
                        int shift, int N) {
    int b = blockIdx.x;
    long long n0 = (long long)b << shift; if (n0 > N) n0 = N;
    long long n1 = (long long)(b + 1) << shift; if (n1 > N) n1 = N;
    int s0 = rowptr[n0], s1 = rowptr[n1];
    unsigned mask = (1u << shift) - 1u;
    for (int i = s0 + (int)threadIdx.x; i < s1; i += 256) {
        unsigned long long p = stg[i];
        int dlow = (int)(p & mask);
        int s = (int)((p >> 12) & 0xFFFFFFFu);
        int eid = (int)(p >> 40);
        int d = (b << shift) | dlow;
        int pos = rowptr[d] + atomicAdd(&fill[d], 1);
        csr_ea[pos] = ea[(unsigned)eid];
        csr_src[pos] = s;
    }
}

// Single-pass scatter fallback (two random stores/edge; only used if the
// radix packing limits don't hold).
__global__ void k_scatter(const int* __restrict__ src, const int* __restrict__ dst,
                          const float4* __restrict__ ea,
                          const int* __restrict__ rowptr, int* __restrict__ fill,
                          float4* __restrict__ csr_ea, int* __restrict__ csr_src,
                          int E) {
    int e = blockIdx.x * blockDim.x + threadIdx.x;
    if (e >= E) return;
    int d = dst[e];
    int pos = rowptr[d] + atomicAdd(&fill[d], 1);
    csr_ea[pos] = ea[e];
    csr_src[pos] = src[e];
}

// Fused GATv2 logits + segment-softmax + aggregation, node-parallel,
// EDGE-QUAD layout: wave = 1 node; lane l: group g=l>>4 owns edge slot jb+g,
// lane q=l&15 owns channels 4q..4q+3 (head q>>2) as float4.
__global__ void k_gat_agg(const int* __restrict__ rowptr,
                          const int* __restrict__ csr_src,   // [E] CSR-ordered
                          const float4* __restrict__ csr_ea, // [E] CSR-ordered
                          const float* __restrict__ xl,   // [N,64]
                          const float* __restrict__ xr,   // [N,64]
                          const float* __restrict__ We,   // [4,64]
                          const float* __restrict__ att,  // [64]
                          const float* __restrict__ bias, // [64]
                          float* __restrict__ out,        // [N,64]
                          int N, int elu) {
    int l = threadIdx.x & 63;
    int n = blockIdx.x * 4 + (threadIdx.x >> 6);
    if (n >= N) return;
    int q = l & 15;
    int g = l >> 4;
    int f4 = q * 4;
    const float LOG2E = 1.44269504088896f;

    float4 w0 = *(const float4*)&We[f4];
    float4 w1 = *(const float4*)&We[64 + f4];
    float4 w2 = *(const float4*)&We[128 + f4];
    float4 w3 = *(const float4*)&We[192 + f4];
    float4 at = *(const float4*)&att[f4];
    at.x *= LOG2E; at.y *= LOG2E; at.z *= LOG2E; at.w *= LOG2E;
    float4 xr4 = *(const float4*)&xr[(size_t)n * 64 + f4];

    int beg = rowptr[n], end = rowptr[n + 1];
    const float4* xl4 = (const float4*)xl;

    float m = -1e30f, den = 0.f;
    float4 acc = make_float4(0.f, 0.f, 0.f, 0.f);

    for (int jb = beg; jb < end; jb += 4) {
        int j = jb + g;
        bool valid = (j < end);
        int jj = valid ? j : end - 1;
        int s = csr_src[jj];
        float4 a = csr_ea[jj];
        float4 xv = xl4[(unsigned)s * 16u + (unsigned)q];
        float vx = fmaf(a.x, w0.x, fmaf(a.y, w1.x, fmaf(a.z, w2.x, fmaf(a.w, w3.x, xr4.x)))) + xv.x;
        float vy = fmaf(a.x, w0.y, fmaf(a.y, w1.y, fmaf(a.z, w2.y, fmaf(a.w, w3.y, xr4.y)))) + xv.y;
        float vz = fmaf(a.x, w0.z, fmaf(a.y, w1.z, fmaf(a.z, w2.z, fmaf(a.w, w3.z, xr4.z)))) + xv.z;
        float vw = fmaf(a.x, w0.w, fmaf(a.y, w1.w, fmaf(a.z, w2.w, fmaf(a.w, w3.w, xr4.w)))) + xv.w;
        vx = fmaxf(vx, 0.2f * vx);
        vy = fmaxf(vy, 0.2f * vy);
        vz = fmaxf(vz, 0.2f * vz);
        vw = fmaxf(vw, 0.2f * vw);
        float pv = fmaf(vx, at.x, fmaf(vy, at.y, fmaf(vz, at.z, vw * at.w)));
        pv = red4(pv);
        pv = valid ? pv : -3.0e38f;
        float mn = fmaxf(m, pv);
        float sc = fexp2(m - mn);
        float e  = fexp2(pv - mn);
        den = fmaf(den, sc, e);
        acc.x = fmaf(e, xv.x, acc.x * sc);
        acc.y = fmaf(e, xv.y, acc.y * sc);
        acc.z = fmaf(e, xv.z, acc.z * sc);
        acc.w = fmaf(e, xv.w, acc.w * sc);
        m = mn;
    }

#pragma unroll
    for (int mask = 16; mask <= 32; mask <<= 1) {
        float m2 = __shfl_xor(m, mask);
        float d2 = __shfl_xor(den, mask);
        float ax = __shfl_xor(acc.x, mask);
        float ay = __shfl_xor(acc.y, mask);
        float az = __shfl_xor(acc.z, mask);
        float aw = __shfl_xor(acc.w, mask);
        float mn = fmaxf(m, m2);
        float s1 = fexp2(m - mn);
        float s2 = fexp2(m2 - mn);
        den = den * s1 + d2 * s2;
        acc.x = acc.x * s1 + ax * s2;
        acc.y = acc.y * s1 + ay * s2;
        acc.z = acc.z * s1 + az * s2;
        acc.w = acc.w * s1 + aw * s2;
        m = mn;
    }

    float inv = (den > 0.f) ? 1.f / den : 0.f;
    float4 b4 = *(const float4*)&bias[f4];
    float4 val;
    val.x = fmaf(acc.x, inv, b4.x);
    val.y = fmaf(acc.y, inv, b4.y);
    val.z = fmaf(acc.z, inv, b4.z);
    val.w = fmaf(acc.w, inv, b4.w);
    if (elu) {
        val.x = (val.x > 0.f) ? val.x : expm1f(val.x);
        val.y = (val.y > 0.f) ? val.y : expm1f(val.y);
        val.z = (val.z > 0.f) ? val.z : expm1f(val.z);
        val.w = (val.w > 0.f) ? val.w : expm1f(val.w);
    }
    if (l < 16) ((float4*)out)[(size_t)n * 16 + q] = val;
}

// Run-length accumulating pool.
__global__ void k_pool(const float* __restrict__ y2,
                       const int* __restrict__ batch,
                       float* __restrict__ pool, float* __restrict__ cnt, int N) {
    const int CH = 256;
    int f = threadIdx.x & 63;
    int lane = threadIdx.x >> 6;
    int base = blockIdx.x * CH;
    int curg = -1;
    float acc = 0.f;
    float c = 0.f;
    for (int n = base + lane; n < base + CH && n < N; n += 4) {
        int g = batch[n];
        if (g != curg) {
            if (curg >= 0) {
                atomicAdd(pool + (size_t)curg * 64 + f, acc);
                if (f == 0) atomicAdd(cnt + curg, c);
            }
            curg = g; acc = 0.f; c = 0.f;
        }
        acc += y2[(size_t)n * 64 + f];
        c += 1.f;
    }
    if (curg >= 0) {
        atomicAdd(pool + (size_t)curg * 64 + f, acc);
        if (f == 0) atomicAdd(cnt + curg, c);
    }
}

// One block (64 threads) per graph: mean, 3 MLP heads.
__global__ void k_head(const float* __restrict__ pool, const float* __restrict__ cnt,
                       const float* __restrict__ Wg1, const float* __restrict__ bg1,
                       const float* __restrict__ Wg2, const float* __restrict__ bg2,
                       const float* __restrict__ Wp, const float* __restrict__ bp,
                       const float* __restrict__ Wc1, const float* __restrict__ bc1,
                       const float* __restrict__ Wc2, const float* __restrict__ bc2,
                       float* __restrict__ out) {
    int g = blockIdx.x, f = threadIdx.x;
    __shared__ float sg[64];
    __shared__ float sh[64];
    float inv = 1.f / fmaxf(cnt[g], 1.f);
    sg[f] = pool[(size_t)g * 64 + f] * inv;
    __syncthreads();
    float acc = bg1[f];
    for (int k = 0; k < 64; ++k) acc += sg[k] * Wg1[k * 64 + f];
    sh[f] = fmaxf(acc, 0.f);
    __syncthreads();
    if (f < 15) {
        float o = bg2[f];
        for (int k = 0; k < 64; ++k) o += sh[k] * Wg2[k * 15 + f];
        out[(size_t)g * 15 + f] = o;
    }
    if (f < 10) {
        float o = bp[f];
        for (int k = 0; k < 64; ++k) o += sg[k] * Wp[k * 10 + f];
        out[960 + (size_t)g * 10 + f] = o;
    }
    __syncthreads();
    float acc2 = bc1[f];
    for (int k = 0; k < 64; ++k) acc2 += sg[k] * Wc1[k * 64 + f];
    sh[f] = fmaxf(acc2, 0.f);
    __syncthreads();
    if (f == 0) {
        float v = bc2[0];
        for (int k = 0; k < 64; ++k) v += sh[k] * Wc2[k];
        out[1600 + g] = v;
    }
}

extern "C" void kernel_launch(void* const* d_in, const int* in_sizes, int n_in,
                              void* d_out, int out_size, void* d_ws, size_t ws_size,
                              hipStream_t stream) {
    const float* x     = (const float*)d_in[0];
    const int*   ei    = (const int*)d_in[1];
    const float* ea    = (const float*)d_in[2];
    const int*   batch = (const int*)d_in[3];
    const float* Wl1 = (const float*)d_in[4];
    const float* Wr1 = (const float*)d_in[5];
    const float* We1 = (const float*)d_in[6];
    const float* att1 = (const float*)d_in[7];
    const float* b1  = (const float*)d_in[8];
    const float* Wl2 = (const float*)d_in[9];
    const float* Wr2 = (const float*)d_in[10];
    const float* We2 = (const float*)d_in[11];
    const float* att2 = (const float*)d_in[12];
    const float* b2  = (const float*)d_in[13];
    const float* Wg1 = (const float*)d_in[14];
    const float* bg1 = (const float*)d_in[15];
    const float* Wg2 = (const float*)d_in[16];
    const float* bg2 = (const float*)d_in[17];
    const float* Wp  = (const float*)d_in[18];
    const float* bp  = (const float*)d_in[19];
    const float* Wc1 = (const float*)d_in[20];
    const float* bc1 = (const float*)d_in[21];
    const float* Wc2 = (const float*)d_in[22];
    const float* bc2 = (const float*)d_in[23];

    const int N = in_sizes[0] / 16;       // 100000
    const int E = in_sizes[2] / 4;        // 1600000
    const int* src = ei;
    const int* dst = ei + E;

    // bucket shift: B = ceil(N >> shift) <= 512
    int shift = 8;
    while (((N + (1 << shift) - 1) >> shift) > 512) ++shift;
    int B = (N + (1 << shift) - 1) >> shift;
    // packing limits: dst_low <= 12 bits, src <= 28 bits, eid <= 24 bits
    bool radix = (shift <= 12) && (N <= (1 << 28)) && (E < (1 << 24));

    // workspace layout (bytes)
    size_t NF = (size_t)N * 64;
    char* w = (char*)d_ws;
    float* A  = (float*)w; w += NF * 4;
    float* B_ = (float*)w; w += NF * 4;
    float* C  = (float*)w; w += NF * 4;
    float4* csr_ea = (float4*)w; w += (size_t)E * 16;
    int* csr_src   = (int*)w;    w += (size_t)E * 4;
    int* rowptr = (int*)w; w += (size_t)(N + 1) * 4;
    int* deg    = (int*)w; w += (size_t)N * 4;      // reused as fill
    int* spart  = (int*)w; w += (size_t)N * 4;
    int* bsum   = (int*)w; w += 128 * 4;
    int* bfill  = (int*)w; w += 513 * 4;
    float* PL   = (float*)w; w += 4096 * 4;
    float* CT   = (float*)w;
    // staging overlays A (E*8 = 12.8MB <= NF*4 = 25.6MB); lin1 runs later
    unsigned long long* stg = (unsigned long long*)A;
    radix = radix && ((size_t)E * 8 <= NF * 4);

    dim3 blk(256);
    int gE  = (E + 255) / 256;
    int gN  = (N + 255) / 256;
    int nb1 = (N + 1023) / 1024;
    int gAgg = (N + 3) / 4;
    int gLin = (N + 63) / 64;

    // ---- CSR build (shared by both layers) ----
    hipMemsetAsync(deg, 0, (size_t)N * sizeof(int), stream);
    k_deg<<<gE, blk, 0, stream>>>(dst, deg, E);
    k_scan1<<<nb1, blk, 0, stream>>>(deg, spart, bsum, N);
    k_scan2<<<1, 128, 0, stream>>>(bsum, nb1);
    k_scan3<<<gN, blk, 0, stream>>>(spart, bsum, rowptr, N);
    hipMemsetAsync(deg, 0, (size_t)N * sizeof(int), stream);  // reuse as fill
    if (radix) {
        k_binit<<<(B + 255) / 256, blk, 0, stream>>>(rowptr, bfill, shift, B, N);
        int gridA = 512;
        int chunk = (E + gridA - 1) / gridA;
        k_part<<<gridA, blk, 0, stream>>>(src, dst, bfill, stg, shift, E, chunk);
        k_scat2<<<B, blk, 0, stream>>>(stg, (const float4*)ea, rowptr, deg,
                                       csr_ea, csr_src, shift, N);
    } else {
        k_scatter<<<gE, blk, 0, stream>>>(src, dst, (const float4*)ea,
                                          rowptr, deg, csr_ea, csr_src, E);
    }

    // ---- Layer 1 ---- (A free now: staging no longer needed)
    k_lin_tiled<16><<<gLin, blk, 0, stream>>>(x, Wl1, Wr1, A, B_, N);
    k_gat_agg<<<gAgg, blk, 0, stream>>>(rowptr, csr_src, csr_ea, A, B_,
                                        We1, att1, b1, C, N, 1);

    // ---- Layer 2 ---- (xl2 -> B_, xr2 -> A)
    k_lin_tiled<64><<<gLin, blk, 0, stream>>>(C, Wl2, Wr2, B_, A, N);
    k_gat_agg<<<gAgg, blk, 0, stream>>>(rowptr, csr_src, csr_ea, B_, A,
                                        We2, att2, b2, C, N, 0);

    // ---- Pool + heads ----
    hipMemsetAsync(PL, 0, (4096 + 64) * sizeof(float), stream);
    k_pool<<<(N + 255) / 256, blk, 0, stream>>>(C, batch, PL, CT, N);
    k_head<<<64, 64, 0, stream>>>(PL, CT, Wg1, bg1, Wg2, bg2, Wp, bp,
                                  Wc1, bc1, Wc2, bc2, (float*)d_out);
}

// Round 16
// 460.916 us; speedup vs baseline: 1.0587x; 1.0587x over previous
//
#include <hip/hip_runtime.h>

#define DEVINL __device__ __forceinline__

#if __has_builtin(__builtin_amdgcn_exp2f)
DEVINL float fexp2(float x) { return __builtin_amdgcn_exp2f(x); }
#else
DEVINL float fexp2(float x) { return exp2f(x); }
#endif

// Sum over the 4 channel-quad lanes of a head (lane^1, lane^2) via ds_swizzle
// XOR immediates (BitMode: offset = (xor<<10) | 0x1F).
DEVINL float red4(float pv) {
    pv += __int_as_float(__builtin_amdgcn_ds_swizzle(__float_as_int(pv), 0x041F));
    pv += __int_as_float(__builtin_amdgcn_ds_swizzle(__float_as_int(pv), 0x081F));
    return pv;
}

// LDS-tiled GEMM: out[n, 0:128] = x[n, 0:K] @ [Wa | Wb].
template <int K>
__global__ void k_lin_tiled(const float* __restrict__ x,
                            const float* __restrict__ Wa,
                            const float* __restrict__ Wb,
                            float* __restrict__ oa, float* __restrict__ ob,
                            int N) {
    __shared__ float sx[64 * K];
    __shared__ float sw[K * 128];
    int t = threadIdx.x;
    int base = blockIdx.x * 64;

    const int WTOT = K * 64 / 4;
    for (int i = t; i < WTOT; i += 256) {
        float4 wa = ((const float4*)Wa)[i];
        float4 wb = ((const float4*)Wb)[i];
        int k = (i * 4) >> 6, f = (i * 4) & 63;
        *(float4*)&sw[k * 128 + f] = wa;
        *(float4*)&sw[k * 128 + 64 + f] = wb;
    }
    const int XTOT = 64 * K / 4;
    for (int i = t; i < XTOT; i += 256) {
        int n = (i * 4) / K, kk = (i * 4) % K;
        float4 v = make_float4(0.f, 0.f, 0.f, 0.f);
        if (base + n < N) v = *(const float4*)&x[(size_t)(base + n) * K + kk];
        *(float4*)&sx[n * K + kk] = v;
    }
    __syncthreads();

    int fq = t & 31;
    int nq = t >> 5;
    float acc[8][4];
#pragma unroll
    for (int i = 0; i < 8; ++i)
#pragma unroll
        for (int c = 0; c < 4; ++c) acc[i][c] = 0.f;

    for (int k0 = 0; k0 < K; k0 += 4) {
        float4 xv[8];
#pragma unroll
        for (int i = 0; i < 8; ++i)
            xv[i] = *(const float4*)&sx[(nq * 8 + i) * K + k0];
#pragma unroll
        for (int kk = 0; kk < 4; ++kk) {
            float4 w = *(const float4*)&sw[(k0 + kk) * 128 + fq * 4];
#pragma unroll
            for (int i = 0; i < 8; ++i) {
                float xs = (kk == 0) ? xv[i].x : (kk == 1) ? xv[i].y
                         : (kk == 2) ? xv[i].z : xv[i].w;
                acc[i][0] = fmaf(xs, w.x, acc[i][0]);
                acc[i][1] = fmaf(xs, w.y, acc[i][1]);
                acc[i][2] = fmaf(xs, w.z, acc[i][2]);
                acc[i][3] = fmaf(xs, w.w, acc[i][3]);
            }
        }
    }

    int col = fq * 4;
    float* o = (col < 64) ? oa : ob;
    int c = col & 63;
#pragma unroll
    for (int i = 0; i < 8; ++i) {
        int n = base + nq * 8 + i;
        if (n < N)
            *(float4*)&o[(size_t)n * 64 + c] =
                make_float4(acc[i][0], acc[i][1], acc[i][2], acc[i][3]);
    }
}

// ---- CSR build ----
__global__ void k_deg(const int* __restrict__ dst, int* __restrict__ deg, int E) {
    int e = blockIdx.x * blockDim.x + threadIdx.x;
    if (e < E) atomicAdd(&deg[dst[e]], 1);
}

__global__ void k_scan1(const int* __restrict__ deg, int* __restrict__ spart,
                        int* __restrict__ bsum, int N) {
    __shared__ int sh[256];
    int base = blockIdx.x * 1024;
    int t = threadIdx.x;
    int v[4]; int sum = 0;
#pragma unroll
    for (int i = 0; i < 4; ++i) {
        int idx = base + t * 4 + i;
        v[i] = (idx < N) ? deg[idx] : 0;
        sum += v[i];
    }
    sh[t] = sum;
    __syncthreads();
    for (int off = 1; off < 256; off <<= 1) {
        int x = (t >= off) ? sh[t - off] : 0;
        __syncthreads();
        sh[t] += x;
        __syncthreads();
    }
    int run = (t > 0) ? sh[t - 1] : 0;
#pragma unroll
    for (int i = 0; i < 4; ++i) {
        run += v[i];
        int idx = base + t * 4 + i;
        if (idx < N) spart[idx] = run;
    }
    if (t == 255) bsum[blockIdx.x] = sh[255];
}

__global__ void k_scan2(int* __restrict__ bsum, int nb) {
    __shared__ int sh[128];
    int t = threadIdx.x;
    sh[t] = (t < nb) ? bsum[t] : 0;
    __syncthreads();
    for (int off = 1; off < 128; off <<= 1) {
        int x = (t >= off) ? sh[t - off] : 0;
        __syncthreads();
        sh[t] += x;
        __syncthreads();
    }
    if (t < nb) bsum[t] = (t > 0) ? sh[t - 1] : 0;
}

__global__ void k_scan3(const int* __restrict__ spart, const int* __restrict__ bsum,
                        int* __restrict__ rowptr, int N) {
    int i = blockIdx.x * blockDim.x + threadIdx.x;
    if (i < N) rowptr[i + 1] = spart[i] + bsum[i >> 10];
    if (i == 0) rowptr[0] = 0;
}

// bucket fill init: bfill[b] = rowptr[min(b<<shift, N)]
__global__ void k_binit(const int* __restrict__ rowptr, int* __restrict__ bfill,
                        int shift, int B, int N) {
    int b = blockIdx.x * blockDim.x + threadIdx.x;
    if (b < B) {
        long long node = (long long)b << shift;
        if (node > N) node = N;
        bfill[b] = rowptr[node];
    }
}

// Pass A: partition edges into dst-range buckets (bucket = dst>>shift).
// 8B staging record: {eid:24 | src:28 | dst_low:12}.
__global__ void k_part(const int* __restrict__ src, const int* __restrict__ dst,
                       int* __restrict__ bfill, unsigned long long* __restrict__ stg,
                       int shift, int E, int chunk) {
    __shared__ int hist[512];
    __shared__ int base[512];
    int t = threadIdx.x;
    int e0 = blockIdx.x * chunk;
    int e1 = e0 + chunk; if (e1 > E) e1 = E;
    for (int i = t; i < 512; i += 256) hist[i] = 0;
    __syncthreads();
    for (int e = e0 + t; e < e1; e += 256)
        atomicAdd(&hist[(unsigned)dst[e] >> shift], 1);
    __syncthreads();
    for (int i = t; i < 512; i += 256) {
        int h = hist[i];
        base[i] = h ? atomicAdd(&bfill[i], h) : 0;
    }
    __syncthreads();
    for (int i = t; i < 512; i += 256) hist[i] = 0;
    __syncthreads();
    unsigned mask = (1u << shift) - 1u;
    for (int e = e0 + t; e < e1; e += 256) {
        int d = dst[e];
        int b = (unsigned)d >> shift;
        int off = atomicAdd(&hist[b], 1);
        unsigned long long p = ((unsigned long long)(unsigned)e << 40)
                             | ((unsigned long long)(unsigned)src[e] << 12)
                             | (unsigned long long)((unsigned)d & mask);
        stg[(size_t)(base[b] + off)] = p;
    }
}

// Pass B: one block per bucket; scatter within the bucket's contiguous CSR
// range -> all of a line's writes come from ONE block/CU/L2.
__global__ void k_scat2(const unsigned long long* __restrict__ stg,
                        const int* __restrict__ rowptr, int* __restrict__ fill,
                        int2* __restrict__ csr, int shift, int N) {
    int b = blockIdx.x;
    long long n0 = (long long)b << shift; if (n0 > N) n0 = N;
    long long n1 = (long long)(b + 1) << shift; if (n1 > N) n1 = N;
    int s0 = rowptr[n0], s1 = rowptr[n1];
    unsigned mask = (1u << shift) - 1u;
    for (int i = s0 + (int)threadIdx.x; i < s1; i += 256) {
        unsigned long long p = stg[i];
        int dlow = (int)(p & mask);
        int s = (int)((p >> 12) & 0xFFFFFFFu);
        int eid = (int)(p >> 40);
        int d = (b << shift) | dlow;
        int pos = rowptr[d] + atomicAdd(&fill[d], 1);
        csr[pos] = make_int2(s, eid);
    }
}

// Single-pass scatter fallback.
__global__ void k_scatter(const int* __restrict__ src, const int* __restrict__ dst,
                          const int* __restrict__ rowptr, int* __restrict__ fill,
                          int2* __restrict__ csr, int E) {
    int e = blockIdx.x * blockDim.x + threadIdx.x;
    if (e >= E) return;
    int d = dst[e];
    int pos = rowptr[d] + atomicAdd(&fill[d], 1);
    csr[pos] = make_int2(src[e], e);
}

// Per-edge quad logit (log2 domain): returns per-head logit for this lane's
// channel quad after red4; xv returned by ref.
DEVINL float quad_logit(float4 a, float4 xv, float4 xr4,
                        float4 w0, float4 w1, float4 w2, float4 w3, float4 at) {
    float vx = fmaf(a.x, w0.x, fmaf(a.y, w1.x, fmaf(a.z, w2.x, fmaf(a.w, w3.x, xr4.x)))) + xv.x;
    float vy = fmaf(a.x, w0.y, fmaf(a.y, w1.y, fmaf(a.z, w2.y, fmaf(a.w, w3.y, xr4.y)))) + xv.y;
    float vz = fmaf(a.x, w0.z, fmaf(a.y, w1.z, fmaf(a.z, w2.z, fmaf(a.w, w3.z, xr4.z)))) + xv.z;
    float vw = fmaf(a.x, w0.w, fmaf(a.y, w1.w, fmaf(a.z, w2.w, fmaf(a.w, w3.w, xr4.w)))) + xv.w;
    vx = fmaxf(vx, 0.2f * vx);
    vy = fmaxf(vy, 0.2f * vy);
    vz = fmaxf(vz, 0.2f * vz);
    vw = fmaxf(vw, 0.2f * vw);
    float pv = fmaf(vx, at.x, fmaf(vy, at.y, fmaf(vz, at.z, vw * at.w)));
    return red4(pv);
}

// Fused GATv2 logits + segment-softmax + aggregation, node-parallel,
// EDGE-QUAD layout + deferred-max softmax + 2x unroll (8 edges in flight).
__global__ void k_gat_agg(const int* __restrict__ rowptr,
                          const int2* __restrict__ csr,   // {src, eid}
                          const float4* __restrict__ ea,  // [E] edge_attr
                          const float* __restrict__ xl,   // [N,64]
                          const float* __restrict__ xr,   // [N,64]
                          const float* __restrict__ We,   // [4,64]
                          const float* __restrict__ att,  // [64]
                          const float* __restrict__ bias, // [64]
                          float* __restrict__ out,        // [N,64]
                          int N, int elu) {
    int l = threadIdx.x & 63;
    int n = blockIdx.x * 4 + (threadIdx.x >> 6);
    if (n >= N) return;
    int q = l & 15;
    int g = l >> 4;
    int f4 = q * 4;
    const float LOG2E = 1.44269504088896f;

    float4 w0 = *(const float4*)&We[f4];
    float4 w1 = *(const float4*)&We[64 + f4];
    float4 w2 = *(const float4*)&We[128 + f4];
    float4 w3 = *(const float4*)&We[192 + f4];
    float4 at = *(const float4*)&att[f4];
    at.x *= LOG2E; at.y *= LOG2E; at.z *= LOG2E; at.w *= LOG2E;
    float4 xr4 = *(const float4*)&xr[(size_t)n * 64 + f4];

    int beg = rowptr[n], end = rowptr[n + 1];
    const float4* xl4 = (const float4*)xl;

    float m = -1e30f, den = 0.f;
    float4 acc = make_float4(0.f, 0.f, 0.f, 0.f);

    int jb = beg;
    // main loop: 8 edges in flight (two quads), all valid
    for (; jb + 8 <= end; jb += 8) {
        int2 se0 = csr[jb + g];
        int2 se1 = csr[jb + 4 + g];
        float4 a0 = ea[(unsigned)se0.y];
        float4 a1 = ea[(unsigned)se1.y];
        float4 xv0 = xl4[(unsigned)se0.x * 16u + (unsigned)q];
        float4 xv1 = xl4[(unsigned)se1.x * 16u + (unsigned)q];
        float p0 = quad_logit(a0, xv0, xr4, w0, w1, w2, w3, at);
        float p1 = quad_logit(a1, xv1, xr4, w0, w1, w2, w3, at);
        if (__any(fmaxf(p0, p1) - m > 8.f)) {      // first iter + rare growth
            float mn = fmaxf(m, fmaxf(p0, p1));
            float sc = fexp2(m - mn);
            float e0 = fexp2(p0 - mn), e1 = fexp2(p1 - mn);
            den = fmaf(den, sc, e0 + e1);
            acc.x = fmaf(e0, xv0.x, fmaf(e1, xv1.x, acc.x * sc));
            acc.y = fmaf(e0, xv0.y, fmaf(e1, xv1.y, acc.y * sc));
            acc.z = fmaf(e0, xv0.z, fmaf(e1, xv1.z, acc.z * sc));
            acc.w = fmaf(e0, xv0.w, fmaf(e1, xv1.w, acc.w * sc));
            m = mn;
        } else {                                    // fast path: 2 exp2 only
            float e0 = fexp2(p0 - m), e1 = fexp2(p1 - m);
            den += e0 + e1;
            acc.x = fmaf(e0, xv0.x, fmaf(e1, xv1.x, acc.x));
            acc.y = fmaf(e0, xv0.y, fmaf(e1, xv1.y, acc.y));
            acc.z = fmaf(e0, xv0.z, fmaf(e1, xv1.z, acc.z));
            acc.w = fmaf(e0, xv0.w, fmaf(e1, xv1.w, acc.w));
        }
    }
    // tail: up to 7 edges, masked quad
    for (; jb < end; jb += 4) {
        int j = jb + g;
        bool valid = (j < end);
        int jj = valid ? j : end - 1;
        int2 se = csr[jj];
        float4 a = ea[(unsigned)se.y];
        float4 xv = xl4[(unsigned)se.x * 16u + (unsigned)q];
        float pv = quad_logit(a, xv, xr4, w0, w1, w2, w3, at);
        pv = valid ? pv : -3.0e38f;
        if (__any(pv - m > 8.f)) {
            float mn = fmaxf(m, pv);
            float sc = fexp2(m - mn);
            float e = fexp2(pv - mn);
            den = fmaf(den, sc, e);
            acc.x = fmaf(e, xv.x, acc.x * sc);
            acc.y = fmaf(e, xv.y, acc.y * sc);
            acc.z = fmaf(e, xv.z, acc.z * sc);
            acc.w = fmaf(e, xv.w, acc.w * sc);
            m = mn;
        } else {
            float e = fexp2(pv - m);
            den += e;
            acc.x = fmaf(e, xv.x, acc.x);
            acc.y = fmaf(e, xv.y, acc.y);
            acc.z = fmaf(e, xv.z, acc.z);
            acc.w = fmaf(e, xv.w, acc.w);
        }
    }

    // merge the 4 group states (flash-style), lanes l^16 then l^32
#pragma unroll
    for (int mask = 16; mask <= 32; mask <<= 1) {
        float m2 = __shfl_xor(m, mask);
        float d2 = __shfl_xor(den, mask);
        float ax = __shfl_xor(acc.x, mask);
        float ay = __shfl_xor(acc.y, mask);
        float az = __shfl_xor(acc.z, mask);
        float aw = __shfl_xor(acc.w, mask);
        float mn = fmaxf(m, m2);
        float s1 = fexp2(m - mn);
        float s2 = fexp2(m2 - mn);
        den = den * s1 + d2 * s2;
        acc.x = acc.x * s1 + ax * s2;
        acc.y = acc.y * s1 + ay * s2;
        acc.z = acc.z * s1 + az * s2;
        acc.w = acc.w * s1 + aw * s2;
        m = mn;
    }

    float inv = (den > 0.f) ? 1.f / den : 0.f;
    float4 b4 = *(const float4*)&bias[f4];
    float4 val;
    val.x = fmaf(acc.x, inv, b4.x);
    val.y = fmaf(acc.y, inv, b4.y);
    val.z = fmaf(acc.z, inv, b4.z);
    val.w = fmaf(acc.w, inv, b4.w);
    if (elu) {
        val.x = (val.x > 0.f) ? val.x : expm1f(val.x);
        val.y = (val.y > 0.f) ? val.y : expm1f(val.y);
        val.z = (val.z > 0.f) ? val.z : expm1f(val.z);
        val.w = (val.w > 0.f) ? val.w : expm1f(val.w);
    }
    if (l < 16) ((float4*)out)[(size_t)n * 16 + q] = val;
}

// Run-length accumulating pool.
__global__ void k_pool(const float* __restrict__ y2,
                       const int* __restrict__ batch,
                       float* __restrict__ pool, float* __restrict__ cnt, int N) {
    const int CH = 256;
    int f = threadIdx.x & 63;
    int lane = threadIdx.x >> 6;
    int base = blockIdx.x * CH;
    int curg = -1;
    float acc = 0.f;
    float c = 0.f;
    for (int n = base + lane; n < base + CH && n < N; n += 4) {
        int g = batch[n];
        if (g != curg) {
            if (curg >= 0) {
                atomicAdd(pool + (size_t)curg * 64 + f, acc);
                if (f == 0) atomicAdd(cnt + curg, c);
            }
            curg = g; acc = 0.f; c = 0.f;
        }
        acc += y2[(size_t)n * 64 + f];
        c += 1.f;
    }
    if (curg >= 0) {
        atomicAdd(pool + (size_t)curg * 64 + f, acc);
        if (f == 0) atomicAdd(cnt + curg, c);
    }
}

// One block (64 threads) per graph: mean, 3 MLP heads.
__global__ void k_head(const float* __restrict__ pool, const float* __restrict__ cnt,
                       const float* __restrict__ Wg1, const float* __restrict__ bg1,
                       const float* __restrict__ Wg2, const float* __restrict__ bg2,
                       const float* __restrict__ Wp, const float* __restrict__ bp,
                       const float* __restrict__ Wc1, const float* __restrict__ bc1,
                       const float* __restrict__ Wc2, const float* __restrict__ bc2,
                       float* __restrict__ out) {
    int g = blockIdx.x, f = threadIdx.x;
    __shared__ float sg[64];
    __shared__ float sh[64];
    float inv = 1.f / fmaxf(cnt[g], 1.f);
    sg[f] = pool[(size_t)g * 64 + f] * inv;
    __syncthreads();
    float acc = bg1[f];
    for (int k = 0; k < 64; ++k) acc += sg[k] * Wg1[k * 64 + f];
    sh[f] = fmaxf(acc, 0.f);
    __syncthreads();
    if (f < 15) {
        float o = bg2[f];
        for (int k = 0; k < 64; ++k) o += sh[k] * Wg2[k * 15 + f];
        out[(size_t)g * 15 + f] = o;
    }
    if (f < 10) {
        float o = bp[f];
        for (int k = 0; k < 64; ++k) o += sg[k] * Wp[k * 10 + f];
        out[960 + (size_t)g * 10 + f] = o;
    }
    __syncthreads();
    float acc2 = bc1[f];
    for (int k = 0; k < 64; ++k) acc2 += sg[k] * Wc1[k * 64 + f];
    sh[f] = fmaxf(acc2, 0.f);
    __syncthreads();
    if (f == 0) {
        float v = bc2[0];
        for (int k = 0; k < 64; ++k) v += sh[k] * Wc2[k];
        out[1600 + g] = v;
    }
}

extern "C" void kernel_launch(void* const* d_in, const int* in_sizes, int n_in,
                              void* d_out, int out_size, void* d_ws, size_t ws_size,
                              hipStream_t stream) {
    const float* x     = (const float*)d_in[0];
    const int*   ei    = (const int*)d_in[1];
    const float* ea    = (const float*)d_in[2];
    const int*   batch = (const int*)d_in[3];
    const float* Wl1 = (const float*)d_in[4];
    const float* Wr1 = (const float*)d_in[5];
    const float* We1 = (const float*)d_in[6];
    const float* att1 = (const float*)d_in[7];
    const float* b1  = (const float*)d_in[8];
    const float* Wl2 = (const float*)d_in[9];
    const float* Wr2 = (const float*)d_in[10];
    const float* We2 = (const float*)d_in[11];
    const float* att2 = (const float*)d_in[12];
    const float* b2  = (const float*)d_in[13];
    const float* Wg1 = (const float*)d_in[14];
    const float* bg1 = (const float*)d_in[15];
    const float* Wg2 = (const float*)d_in[16];
    const float* bg2 = (const float*)d_in[17];
    const float* Wp  = (const float*)d_in[18];
    const float* bp  = (const float*)d_in[19];
    const float* Wc1 = (const float*)d_in[20];
    const float* bc1 = (const float*)d_in[21];
    const float* Wc2 = (const float*)d_in[22];
    const float* bc2 = (const float*)d_in[23];

    const int N = in_sizes[0] / 16;       // 100000
    const int E = in_sizes[2] / 4;        // 1600000
    const int* src = ei;
    const int* dst = ei + E;

    // bucket shift: B = ceil(N >> shift) <= 512
    int shift = 8;
    while (((N + (1 << shift) - 1) >> shift) > 512) ++shift;
    int B = (N + (1 << shift) - 1) >> shift;
    // packing limits: dst_low <= 12 bits, src <= 28 bits, eid <= 24 bits
    bool radix = (shift <= 12) && (N <= (1 << 28)) && (E < (1 << 24));

    // workspace layout (bytes)
    size_t NF = (size_t)N * 64;
    char* w = (char*)d_ws;
    float* A  = (float*)w; w += NF * 4;
    float* B_ = (float*)w; w += NF * 4;
    float* C  = (float*)w; w += NF * 4;
    int2* csr = (int2*)w;  w += (size_t)E * 8;
    int* rowptr = (int*)w; w += (size_t)(N + 1) * 4;
    int* deg    = (int*)w; w += (size_t)N * 4;      // reused as fill
    int* spart  = (int*)w; w += (size_t)N * 4;
    int* bsum   = (int*)w; w += 128 * 4;
    int* bfill  = (int*)w; w += 513 * 4;
    float* PL   = (float*)w; w += 4096 * 4;
    float* CT   = (float*)w;
    // staging overlays A (E*8 = 12.8MB <= NF*4 = 25.6MB); lin1 runs later
    unsigned long long* stg = (unsigned long long*)A;
    radix = radix && ((size_t)E * 8 <= NF * 4);

    dim3 blk(256);
    int gE  = (E + 255) / 256;
    int gN  = (N + 255) / 256;
    int nb1 = (N + 1023) / 1024;
    int gAgg = (N + 3) / 4;
    int gLin = (N + 63) / 64;

    // ---- CSR build (shared by both layers) ----
    hipMemsetAsync(deg, 0, (size_t)N * sizeof(int), stream);
    k_deg<<<gE, blk, 0, stream>>>(dst, deg, E);
    k_scan1<<<nb1, blk, 0, stream>>>(deg, spart, bsum, N);
    k_scan2<<<1, 128, 0, stream>>>(bsum, nb1);
    k_scan3<<<gN, blk, 0, stream>>>(spart, bsum, rowptr, N);
    hipMemsetAsync(deg, 0, (size_t)N * sizeof(int), stream);  // reuse as fill
    if (radix) {
        k_binit<<<(B + 255) / 256, blk, 0, stream>>>(rowptr, bfill, shift, B, N);
        int gridA = 512;
        int chunk = (E + gridA - 1) / gridA;
        k_part<<<gridA, blk, 0, stream>>>(src, dst, bfill, stg, shift, E, chunk);
        k_scat2<<<B, blk, 0, stream>>>(stg, rowptr, deg, csr, shift, N);
    } else {
        k_scatter<<<gE, blk, 0, stream>>>(src, dst, rowptr, deg, csr, E);
    }

    // ---- Layer 1 ---- (A free now: staging no longer needed)
    k_lin_tiled<16><<<gLin, blk, 0, stream>>>(x, Wl1, Wr1, A, B_, N);
    k_gat_agg<<<gAgg, blk, 0, stream>>>(rowptr, csr, (const float4*)ea, A, B_,
                                        We1, att1, b1, C, N, 1);

    // ---- Layer 2 ---- (xl2 -> B_, xr2 -> A)
    k_lin_tiled<64><<<gLin, blk, 0, stream>>>(C, Wl2, Wr2, B_, A, N);
    k_gat_agg<<<gAgg, blk, 0, stream>>>(rowptr, csr, (const float4*)ea, B_, A,
                                        We2, att2, b2, C, N, 0);

    // ---- Pool + heads ----
    hipMemsetAsync(PL, 0, (4096 + 64) * sizeof(float), stream);
    k_pool<<<(N + 255) / 256, blk, 0, stream>>>(C, batch, PL, CT, N);
    k_head<<<64, 64, 0, stream>>>(PL, CT, Wg1, bg1, Wg2, bg2, Wp, bp,
                                  Wc1, bc1, Wc2, bc2, (float*)d_out);
}

// Round 17
// 453.295 us; speedup vs baseline: 1.0765x; 1.0168x over previous
//
#include <hip/hip_runtime.h>

#define DEVINL __device__ __forceinline__

#if __has_builtin(__builtin_amdgcn_exp2f)
DEVINL float fexp2(float x) { return __builtin_amdgcn_exp2f(x); }
#else
DEVINL float fexp2(float x) { return exp2f(x); }
#endif

// Sum over the 4 channel-quad lanes of a head (lane^1, lane^2) via ds_swizzle
// XOR immediates (BitMode: offset = (xor<<10) | 0x1F).
DEVINL float red4(float pv) {
    pv += __int_as_float(__builtin_amdgcn_ds_swizzle(__float_as_int(pv), 0x041F));
    pv += __int_as_float(__builtin_amdgcn_ds_swizzle(__float_as_int(pv), 0x081F));
    return pv;
}

// Shared LDS-tiled GEMM body: out[n, 0:128] = x[n, 0:K] @ [Wa | Wb].
template <int K>
DEVINL void lin_body(float* sx, float* sw,
                     const float* __restrict__ x,
                     const float* __restrict__ Wa,
                     const float* __restrict__ Wb,
                     float* __restrict__ oa, float* __restrict__ ob,
                     int N, int base, int t) {
    const int WTOT = K * 64 / 4;
    for (int i = t; i < WTOT; i += 256) {
        float4 wa = ((const float4*)Wa)[i];
        float4 wb = ((const float4*)Wb)[i];
        int k = (i * 4) >> 6, f = (i * 4) & 63;
        *(float4*)&sw[k * 128 + f] = wa;
        *(float4*)&sw[k * 128 + 64 + f] = wb;
    }
    const int XTOT = 64 * K / 4;
    for (int i = t; i < XTOT; i += 256) {
        int n = (i * 4) / K, kk = (i * 4) % K;
        float4 v = make_float4(0.f, 0.f, 0.f, 0.f);
        if (base + n < N) v = *(const float4*)&x[(size_t)(base + n) * K + kk];
        *(float4*)&sx[n * K + kk] = v;
    }
    __syncthreads();

    int fq = t & 31;
    int nq = t >> 5;
    float acc[8][4];
#pragma unroll
    for (int i = 0; i < 8; ++i)
#pragma unroll
        for (int c = 0; c < 4; ++c) acc[i][c] = 0.f;

    for (int k0 = 0; k0 < K; k0 += 4) {
        float4 xv[8];
#pragma unroll
        for (int i = 0; i < 8; ++i)
            xv[i] = *(const float4*)&sx[(nq * 8 + i) * K + k0];
#pragma unroll
        for (int kk = 0; kk < 4; ++kk) {
            float4 w = *(const float4*)&sw[(k0 + kk) * 128 + fq * 4];
#pragma unroll
            for (int i = 0; i < 8; ++i) {
                float xs = (kk == 0) ? xv[i].x : (kk == 1) ? xv[i].y
                         : (kk == 2) ? xv[i].z : xv[i].w;
                acc[i][0] = fmaf(xs, w.x, acc[i][0]);
                acc[i][1] = fmaf(xs, w.y, acc[i][1]);
                acc[i][2] = fmaf(xs, w.z, acc[i][2]);
                acc[i][3] = fmaf(xs, w.w, acc[i][3]);
            }
        }
    }

    int col = fq * 4;
    float* o = (col < 64) ? oa : ob;
    int c = col & 63;
#pragma unroll
    for (int i = 0; i < 8; ++i) {
        int n = base + nq * 8 + i;
        if (n < N)
            *(float4*)&o[(size_t)n * 64 + c] =
                make_float4(acc[i][0], acc[i][1], acc[i][2], acc[i][3]);
    }
}

template <int K>
__global__ void k_lin_tiled(const float* __restrict__ x,
                            const float* __restrict__ Wa,
                            const float* __restrict__ Wb,
                            float* __restrict__ oa, float* __restrict__ ob,
                            int N) {
    __shared__ float sx[64 * K];
    __shared__ float sw[K * 128];
    lin_body<K>(sx, sw, x, Wa, Wb, oa, ob, N, blockIdx.x * 64, threadIdx.x);
}

// ---- CSR build ----
__global__ void k_deg(const int* __restrict__ dst, int* __restrict__ deg, int E) {
    int e = blockIdx.x * blockDim.x + threadIdx.x;
    if (e < E) atomicAdd(&deg[dst[e]], 1);
}

__global__ void k_scan1(const int* __restrict__ deg, int* __restrict__ spart,
                        int* __restrict__ bsum, int N) {
    __shared__ int sh[256];
    int base = blockIdx.x * 1024;
    int t = threadIdx.x;
    int v[4]; int sum = 0;
#pragma unroll
    for (int i = 0; i < 4; ++i) {
        int idx = base + t * 4 + i;
        v[i] = (idx < N) ? deg[idx] : 0;
        sum += v[i];
    }
    sh[t] = sum;
    __syncthreads();
    for (int off = 1; off < 256; off <<= 1) {
        int x = (t >= off) ? sh[t - off] : 0;
        __syncthreads();
        sh[t] += x;
        __syncthreads();
    }
    int run = (t > 0) ? sh[t - 1] : 0;
#pragma unroll
    for (int i = 0; i < 4; ++i) {
        run += v[i];
        int idx = base + t * 4 + i;
        if (idx < N) spart[idx] = run;
    }
    if (t == 255) bsum[blockIdx.x] = sh[255];
}

__global__ void k_scan2(int* __restrict__ bsum, int nb) {
    __shared__ int sh[128];
    int t = threadIdx.x;
    sh[t] = (t < nb) ? bsum[t] : 0;
    __syncthreads();
    for (int off = 1; off < 128; off <<= 1) {
        int x = (t >= off) ? sh[t - off] : 0;
        __syncthreads();
        sh[t] += x;
        __syncthreads();
    }
    if (t < nb) bsum[t] = (t > 0) ? sh[t - 1] : 0;
}

// scan3 + fused binit + fill-zeroing (fill = deg array, dead after scan1).
__global__ void k_scan3(const int* __restrict__ spart, const int* __restrict__ bsum,
                        int* __restrict__ rowptr, int* __restrict__ fill,
                        int* __restrict__ bfill, int shift, int B, int N) {
    int i = blockIdx.x * blockDim.x + threadIdx.x;
    if (i < N) {
        rowptr[i + 1] = spart[i] + bsum[i >> 10];
        fill[i] = 0;
    }
    if (i == 0) rowptr[0] = 0;
    if (i < B) {
        long long node = (long long)i << shift;
        if (node > N) node = N;
        bfill[i] = (node == 0) ? 0
                 : spart[node - 1] + bsum[(int)((node - 1) >> 10)];
    }
}

// Pass A: partition edges into dst-range buckets (bucket = dst>>shift).
// 8B staging record: {eid:24 | src:28 | dst_low:12}.
__global__ void k_part(const int* __restrict__ src, const int* __restrict__ dst,
                       int* __restrict__ bfill, unsigned long long* __restrict__ stg,
                       int shift, int E, int chunk) {
    __shared__ int hist[512];
    __shared__ int base[512];
    int t = threadIdx.x;
    int e0 = blockIdx.x * chunk;
    int e1 = e0 + chunk; if (e1 > E) e1 = E;
    for (int i = t; i < 512; i += 256) hist[i] = 0;
    __syncthreads();
    for (int e = e0 + t; e < e1; e += 256)
        atomicAdd(&hist[(unsigned)dst[e] >> shift], 1);
    __syncthreads();
    for (int i = t; i < 512; i += 256) {
        int h = hist[i];
        base[i] = h ? atomicAdd(&bfill[i], h) : 0;
    }
    __syncthreads();
    for (int i = t; i < 512; i += 256) hist[i] = 0;
    __syncthreads();
    unsigned mask = (1u << shift) - 1u;
    for (int e = e0 + t; e < e1; e += 256) {
        int d = dst[e];
        int b = (unsigned)d >> shift;
        int off = atomicAdd(&hist[b], 1);
        unsigned long long p = ((unsigned long long)(unsigned)e << 40)
                             | ((unsigned long long)(unsigned)src[e] << 12)
                             | (unsigned long long)((unsigned)d & mask);
        stg[(size_t)(base[b] + off)] = p;
    }
}

// Fused: blocks [0,B) = radix pass B (bucket-local scatter); blocks [B,...) =
// lin1 (x @ [Wl1|Wr1]). The two are independent; co-scheduling overlaps
// scat2's latency-bound 392 blocks with lin1's VALU-bound blocks.
__global__ void k_scat2_lin1(const unsigned long long* __restrict__ stg,
                             const int* __restrict__ rowptr, int* __restrict__ fill,
                             int2* __restrict__ csr, int shift, int N, int B,
                             const float* __restrict__ x,
                             const float* __restrict__ Wa,
                             const float* __restrict__ Wb,
                             float* __restrict__ oa, float* __restrict__ ob) {
    __shared__ float sx[64 * 16];
    __shared__ float sw[16 * 128];
    if ((int)blockIdx.x < B) {
        int b = blockIdx.x;
        long long n0 = (long long)b << shift; if (n0 > N) n0 = N;
        long long n1 = (long long)(b + 1) << shift; if (n1 > N) n1 = N;
        int s0 = rowptr[n0], s1 = rowptr[n1];
        unsigned mask = (1u << shift) - 1u;
        for (int i = s0 + (int)threadIdx.x; i < s1; i += 256) {
            unsigned long long p = stg[i];
            int dlow = (int)(p & mask);
            int s = (int)((p >> 12) & 0xFFFFFFFu);
            int eid = (int)(p >> 40);
            int d = (b << shift) | dlow;
            int pos = rowptr[d] + atomicAdd(&fill[d], 1);
            csr[pos] = make_int2(s, eid);
        }
    } else {
        lin_body<16>(sx, sw, x, Wa, Wb, oa, ob, N,
                     ((int)blockIdx.x - B) * 64, threadIdx.x);
    }
}

// Single-pass scatter fallback.
__global__ void k_scatter(const int* __restrict__ src, const int* __restrict__ dst,
                          const int* __restrict__ rowptr, int* __restrict__ fill,
                          int2* __restrict__ csr, int E) {
    int e = blockIdx.x * blockDim.x + threadIdx.x;
    if (e >= E) return;
    int d = dst[e];
    int pos = rowptr[d] + atomicAdd(&fill[d], 1);
    csr[pos] = make_int2(src[e], e);
}

// Per-edge quad logit (log2 domain).
DEVINL float quad_logit(float4 a, float4 xv, float4 xr4,
                        float4 w0, float4 w1, float4 w2, float4 w3, float4 at) {
    float vx = fmaf(a.x, w0.x, fmaf(a.y, w1.x, fmaf(a.z, w2.x, fmaf(a.w, w3.x, xr4.x)))) + xv.x;
    float vy = fmaf(a.x, w0.y, fmaf(a.y, w1.y, fmaf(a.z, w2.y, fmaf(a.w, w3.y, xr4.y)))) + xv.y;
    float vz = fmaf(a.x, w0.z, fmaf(a.y, w1.z, fmaf(a.z, w2.z, fmaf(a.w, w3.z, xr4.z)))) + xv.z;
    float vw = fmaf(a.x, w0.w, fmaf(a.y, w1.w, fmaf(a.z, w2.w, fmaf(a.w, w3.w, xr4.w)))) + xv.w;
    vx = fmaxf(vx, 0.2f * vx);
    vy = fmaxf(vy, 0.2f * vy);
    vz = fmaxf(vz, 0.2f * vz);
    vw = fmaxf(vw, 0.2f * vw);
    float pv = fmaf(vx, at.x, fmaf(vy, at.y, fmaf(vz, at.z, vw * at.w)));
    return red4(pv);
}

// Fused GATv2 logits + segment-softmax + aggregation, node-parallel,
// EDGE-QUAD layout + deferred-max softmax + 2x unroll (8 edges in flight).
__global__ void k_gat_agg(const int* __restrict__ rowptr,
                          const int2* __restrict__ csr,   // {src, eid}
                          const float4* __restrict__ ea,  // [E] edge_attr
                          const float* __restrict__ xl,   // [N,64]
                          const float* __restrict__ xr,   // [N,64]
                          const float* __restrict__ We,   // [4,64]
                          const float* __restrict__ att,  // [64]
                          const float* __restrict__ bias, // [64]
                          float* __restrict__ out,        // [N,64]
                          int N, int elu) {
    int l = threadIdx.x & 63;
    int n = blockIdx.x * 4 + (threadIdx.x >> 6);
    if (n >= N) return;
    int q = l & 15;
    int g = l >> 4;
    int f4 = q * 4;
    const float LOG2E = 1.44269504088896f;

    float4 w0 = *(const float4*)&We[f4];
    float4 w1 = *(const float4*)&We[64 + f4];
    float4 w2 = *(const float4*)&We[128 + f4];
    float4 w3 = *(const float4*)&We[192 + f4];
    float4 at = *(const float4*)&att[f4];
    at.x *= LOG2E; at.y *= LOG2E; at.z *= LOG2E; at.w *= LOG2E;
    float4 xr4 = *(const float4*)&xr[(size_t)n * 64 + f4];

    int beg = rowptr[n], end = rowptr[n + 1];
    const float4* xl4 = (const float4*)xl;

    float m = -1e30f, den = 0.f;
    float4 acc = make_float4(0.f, 0.f, 0.f, 0.f);

    int jb = beg;
    for (; jb + 8 <= end; jb += 8) {
        int2 se0 = csr[jb + g];
        int2 se1 = csr[jb + 4 + g];
        float4 a0 = ea[(unsigned)se0.y];
        float4 a1 = ea[(unsigned)se1.y];
        float4 xv0 = xl4[(unsigned)se0.x * 16u + (unsigned)q];
        float4 xv1 = xl4[(unsigned)se1.x * 16u + (unsigned)q];
        float p0 = quad_logit(a0, xv0, xr4, w0, w1, w2, w3, at);
        float p1 = quad_logit(a1, xv1, xr4, w0, w1, w2, w3, at);
        if (__any(fmaxf(p0, p1) - m > 8.f)) {
            float mn = fmaxf(m, fmaxf(p0, p1));
            float sc = fexp2(m - mn);
            float e0 = fexp2(p0 - mn), e1 = fexp2(p1 - mn);
            den = fmaf(den, sc, e0 + e1);
            acc.x = fmaf(e0, xv0.x, fmaf(e1, xv1.x, acc.x * sc));
            acc.y = fmaf(e0, xv0.y, fmaf(e1, xv1.y, acc.y * sc));
            acc.z = fmaf(e0, xv0.z, fmaf(e1, xv1.z, acc.z * sc));
            acc.w = fmaf(e0, xv0.w, fmaf(e1, xv1.w, acc.w * sc));
            m = mn;
        } else {
            float e0 = fexp2(p0 - m), e1 = fexp2(p1 - m);
            den += e0 + e1;
            acc.x = fmaf(e0, xv0.x, fmaf(e1, xv1.x, acc.x));
            acc.y = fmaf(e0, xv0.y, fmaf(e1, xv1.y, acc.y));
            acc.z = fmaf(e0, xv0.z, fmaf(e1, xv1.z, acc.z));
            acc.w = fmaf(e0, xv0.w, fmaf(e1, xv1.w, acc.w));
        }
    }
    for (; jb < end; jb += 4) {
        int j = jb + g;
        bool valid = (j < end);
        int jj = valid ? j : end - 1;
        int2 se = csr[jj];
        float4 a = ea[(unsigned)se.y];
        float4 xv = xl4[(unsigned)se.x * 16u + (unsigned)q];
        float pv = quad_logit(a, xv, xr4, w0, w1, w2, w3, at);
        pv = valid ? pv : -3.0e38f;
        if (__any(pv - m > 8.f)) {
            float mn = fmaxf(m, pv);
            float sc = fexp2(m - mn);
            float e = fexp2(pv - mn);
            den = fmaf(den, sc, e);
            acc.x = fmaf(e, xv.x, acc.x * sc);
            acc.y = fmaf(e, xv.y, acc.y * sc);
            acc.z = fmaf(e, xv.z, acc.z * sc);
            acc.w = fmaf(e, xv.w, acc.w * sc);
            m = mn;
        } else {
            float e = fexp2(pv - m);
            den += e;
            acc.x = fmaf(e, xv.x, acc.x);
            acc.y = fmaf(e, xv.y, acc.y);
            acc.z = fmaf(e, xv.z, acc.z);
            acc.w = fmaf(e, xv.w, acc.w);
        }
    }

#pragma unroll
    for (int mask = 16; mask <= 32; mask <<= 1) {
        float m2 = __shfl_xor(m, mask);
        float d2 = __shfl_xor(den, mask);
        float ax = __shfl_xor(acc.x, mask);
        float ay = __shfl_xor(acc.y, mask);
        float az = __shfl_xor(acc.z, mask);
        float aw = __shfl_xor(acc.w, mask);
        float mn = fmaxf(m, m2);
        float s1 = fexp2(m - mn);
        float s2 = fexp2(m2 - mn);
        den = den * s1 + d2 * s2;
        acc.x = acc.x * s1 + ax * s2;
        acc.y = acc.y * s1 + ay * s2;
        acc.z = acc.z * s1 + az * s2;
        acc.w = acc.w * s1 + aw * s2;
        m = mn;
    }

    float inv = (den > 0.f) ? 1.f / den : 0.f;
    float4 b4 = *(const float4*)&bias[f4];
    float4 val;
    val.x = fmaf(acc.x, inv, b4.x);
    val.y = fmaf(acc.y, inv, b4.y);
    val.z = fmaf(acc.z, inv, b4.z);
    val.w = fmaf(acc.w, inv, b4.w);
    if (elu) {
        val.x = (val.x > 0.f) ? val.x : expm1f(val.x);
        val.y = (val.y > 0.f) ? val.y : expm1f(val.y);
        val.z = (val.z > 0.f) ? val.z : expm1f(val.z);
        val.w = (val.w > 0.f) ? val.w : expm1f(val.w);
    }
    if (l < 16) ((float4*)out)[(size_t)n * 16 + q] = val;
}

// Run-length accumulating pool.
__global__ void k_pool(const float* __restrict__ y2,
                       const int* __restrict__ batch,
                       float* __restrict__ pool, float* __restrict__ cnt, int N) {
    const int CH = 256;
    int f = threadIdx.x & 63;
    int lane = threadIdx.x >> 6;
    int base = blockIdx.x * CH;
    int curg = -1;
    float acc = 0.f;
    float c = 0.f;
    for (int n = base + lane; n < base + CH && n < N; n += 4) {
        int g = batch[n];
        if (g != curg) {
            if (curg >= 0) {
                atomicAdd(pool + (size_t)curg * 64 + f, acc);
                if (f == 0) atomicAdd(cnt + curg, c);
            }
            curg = g; acc = 0.f; c = 0.f;
        }
        acc += y2[(size_t)n * 64 + f];
        c += 1.f;
    }
    if (curg >= 0) {
        atomicAdd(pool + (size_t)curg * 64 + f, acc);
        if (f == 0) atomicAdd(cnt + curg, c);
    }
}

// One block (64 threads) per graph: mean, 3 MLP heads.
__global__ void k_head(const float* __restrict__ pool, const float* __restrict__ cnt,
                       const float* __restrict__ Wg1, const float* __restrict__ bg1,
                       const float* __restrict__ Wg2, const float* __restrict__ bg2,
                       const float* __restrict__ Wp, const float* __restrict__ bp,
                       const float* __restrict__ Wc1, const float* __restrict__ bc1,
                       const float* __restrict__ Wc2, const float* __restrict__ bc2,
                       float* __restrict__ out) {
    int g = blockIdx.x, f = threadIdx.x;
    __shared__ float sg[64];
    __shared__ float sh[64];
    float inv = 1.f / fmaxf(cnt[g], 1.f);
    sg[f] = pool[(size_t)g * 64 + f] * inv;
    __syncthreads();
    float acc = bg1[f];
    for (int k = 0; k < 64; ++k) acc += sg[k] * Wg1[k * 64 + f];
    sh[f] = fmaxf(acc, 0.f);
    __syncthreads();
    if (f < 15) {
        float o = bg2[f];
        for (int k = 0; k < 64; ++k) o += sh[k] * Wg2[k * 15 + f];
        out[(size_t)g * 15 + f] = o;
    }
    if (f < 10) {
        float o = bp[f];
        for (int k = 0; k < 64; ++k) o += sg[k] * Wp[k * 10 + f];
        out[960 + (size_t)g * 10 + f] = o;
    }
    __syncthreads();
    float acc2 = bc1[f];
    for (int k = 0; k < 64; ++k) acc2 += sg[k] * Wc1[k * 64 + f];
    sh[f] = fmaxf(acc2, 0.f);
    __syncthreads();
    if (f == 0) {
        float v = bc2[0];
        for (int k = 0; k < 64; ++k) v += sh[k] * Wc2[k];
        out[1600 + g] = v;
    }
}

extern "C" void kernel_launch(void* const* d_in, const int* in_sizes, int n_in,
                              void* d_out, int out_size, void* d_ws, size_t ws_size,
                              hipStream_t stream) {
    const float* x     = (const float*)d_in[0];
    const int*   ei    = (const int*)d_in[1];
    const float* ea    = (const float*)d_in[2];
    const int*   batch = (const int*)d_in[3];
    const float* Wl1 = (const float*)d_in[4];
    const float* Wr1 = (const float*)d_in[5];
    const float* We1 = (const float*)d_in[6];
    const float* att1 = (const float*)d_in[7];
    const float* b1  = (const float*)d_in[8];
    const float* Wl2 = (const float*)d_in[9];
    const float* Wr2 = (const float*)d_in[10];
    const float* We2 = (const float*)d_in[11];
    const float* att2 = (const float*)d_in[12];
    const float* b2  = (const float*)d_in[13];
    const float* Wg1 = (const float*)d_in[14];
    const float* bg1 = (const float*)d_in[15];
    const float* Wg2 = (const float*)d_in[16];
    const float* bg2 = (const float*)d_in[17];
    const float* Wp  = (const float*)d_in[18];
    const float* bp  = (const float*)d_in[19];
    const float* Wc1 = (const float*)d_in[20];
    const float* bc1 = (const float*)d_in[21];
    const float* Wc2 = (const float*)d_in[22];
    const float* bc2 = (const float*)d_in[23];

    const int N = in_sizes[0] / 16;       // 100000
    const int E = in_sizes[2] / 4;        // 1600000
    const int* src = ei;
    const int* dst = ei + E;

    // bucket shift: B = ceil(N >> shift) <= 512
    int shift = 8;
    while (((N + (1 << shift) - 1) >> shift) > 512) ++shift;
    int B = (N + (1 << shift) - 1) >> shift;
    // packing limits: dst_low <= 12 bits, src <= 28 bits, eid <= 24 bits
    bool radix = (shift <= 12) && (N <= (1 << 28)) && (E < (1 << 24));

    // workspace layout (bytes)
    size_t NF = (size_t)N * 64;
    char* w = (char*)d_ws;
    float* A  = (float*)w; w += NF * 4;
    float* B_ = (float*)w; w += NF * 4;
    float* C  = (float*)w; w += NF * 4;
    int2* csr = (int2*)w;  w += (size_t)E * 8;
    int* rowptr = (int*)w; w += (size_t)(N + 1) * 4;
    int* deg    = (int*)w; w += (size_t)N * 4;      // reused as fill
    int* spart  = (int*)w; w += (size_t)N * 4;
    int* bsum   = (int*)w; w += 128 * 4;
    int* bfill  = (int*)w; w += 513 * 4;
    float* PL   = (float*)w; w += 4096 * 4;
    float* CT   = (float*)w;
    // staging overlays C (E*8 = 12.8MB <= NF*4 = 25.6MB); C first written by agg1
    unsigned long long* stg = (unsigned long long*)C;
    radix = radix && ((size_t)E * 8 <= NF * 4);

    dim3 blk(256);
    int gE  = (E + 255) / 256;
    int gN  = (N + 255) / 256;
    int nb1 = (N + 1023) / 1024;
    int gAgg = (N + 3) / 4;
    int gLin = (N + 63) / 64;

    // ---- CSR build (shared by both layers) ----
    hipMemsetAsync(deg, 0, (size_t)N * sizeof(int), stream);
    k_deg<<<gE, blk, 0, stream>>>(dst, deg, E);
    k_scan1<<<nb1, blk, 0, stream>>>(deg, spart, bsum, N);
    k_scan2<<<1, 128, 0, stream>>>(bsum, nb1);
    // scan3 also zeroes `deg` (-> fill) and computes bfill (fused binit)
    k_scan3<<<gN, blk, 0, stream>>>(spart, bsum, rowptr, deg, bfill, shift, B, N);
    if (radix) {
        int gridA = 512;
        int chunk = (E + gridA - 1) / gridA;
        k_part<<<gridA, blk, 0, stream>>>(src, dst, bfill, stg, shift, E, chunk);
        // scat2 (blocks [0,B)) runs concurrently with lin1 (blocks [B, B+gLin))
        k_scat2_lin1<<<B + gLin, blk, 0, stream>>>(stg, rowptr, deg, csr, shift,
                                                   N, B, x, Wl1, Wr1, A, B_);
    } else {
        k_scatter<<<gE, blk, 0, stream>>>(src, dst, rowptr, deg, csr, E);
        k_lin_tiled<16><<<gLin, blk, 0, stream>>>(x, Wl1, Wr1, A, B_, N);
    }

    // ---- Layer 1 ---- (stg dead from here; agg1 overwrites C)
    k_gat_agg<<<gAgg, blk, 0, stream>>>(rowptr, csr, (const float4*)ea, A, B_,
                                        We1, att1, b1, C, N, 1);

    // ---- Layer 2 ---- (xl2 -> B_, xr2 -> A)
    k_lin_tiled<64><<<gLin, blk, 0, stream>>>(C, Wl2, Wr2, B_, A, N);
    k_gat_agg<<<gAgg, blk, 0, stream>>>(rowptr, csr, (const float4*)ea, B_, A,
                                        We2, att2, b2, C, N, 0);

    // ---- Pool + heads ----
    hipMemsetAsync(PL, 0, (4096 + 64) * sizeof(float), stream);
    k_pool<<<(N + 255) / 256, blk, 0, stream>>>(C, batch, PL, CT, N);
    k_head<<<64, 64, 0, stream>>>(PL, CT, Wg1, bg1, Wg2, bg2, Wp, bp,
                                  Wc1, bc1, Wc2, bc2, (float*)d_out);
}

// Round 18
// 448.630 us; speedup vs baseline: 1.0877x; 1.0104x over previous
//
#include <hip/hip_runtime.h>

#define DEVINL __device__ __forceinline__

#if __has_builtin(__builtin_amdgcn_exp2f)
DEVINL float fexp2(float x) { return __builtin_amdgcn_exp2f(x); }
#else
DEVINL float fexp2(float x) { return exp2f(x); }
#endif

// Sum over the 4 channel-quad lanes of a head (lane^1, lane^2) via ds_swizzle
// XOR immediates (BitMode: offset = (xor<<10) | 0x1F).
DEVINL float red4(float pv) {
    pv += __int_as_float(__builtin_amdgcn_ds_swizzle(__float_as_int(pv), 0x041F));
    pv += __int_as_float(__builtin_amdgcn_ds_swizzle(__float_as_int(pv), 0x081F));
    return pv;
}

// LDS-tiled GEMM: out[n, 0:128] = x[n, 0:K] @ [Wa | Wb].
template <int K>
__global__ void k_lin_tiled(const float* __restrict__ x,
                            const float* __restrict__ Wa,
                            const float* __restrict__ Wb,
                            float* __restrict__ oa, float* __restrict__ ob,
                            int N) {
    __shared__ float sx[64 * K];
    __shared__ float sw[K * 128];
    int t = threadIdx.x;
    int base = blockIdx.x * 64;

    const int WTOT = K * 64 / 4;
    for (int i = t; i < WTOT; i += 256) {
        float4 wa = ((const float4*)Wa)[i];
        float4 wb = ((const float4*)Wb)[i];
        int k = (i * 4) >> 6, f = (i * 4) & 63;
        *(float4*)&sw[k * 128 + f] = wa;
        *(float4*)&sw[k * 128 + 64 + f] = wb;
    }
    const int XTOT = 64 * K / 4;
    for (int i = t; i < XTOT; i += 256) {
        int n = (i * 4) / K, kk = (i * 4) % K;
        float4 v = make_float4(0.f, 0.f, 0.f, 0.f);
        if (base + n < N) v = *(const float4*)&x[(size_t)(base + n) * K + kk];
        *(float4*)&sx[n * K + kk] = v;
    }
    __syncthreads();

    int fq = t & 31;
    int nq = t >> 5;
    float acc[8][4];
#pragma unroll
    for (int i = 0; i < 8; ++i)
#pragma unroll
        for (int c = 0; c < 4; ++c) acc[i][c] = 0.f;

    for (int k0 = 0; k0 < K; k0 += 4) {
        float4 xv[8];
#pragma unroll
        for (int i = 0; i < 8; ++i)
            xv[i] = *(const float4*)&sx[(nq * 8 + i) * K + k0];
#pragma unroll
        for (int kk = 0; kk < 4; ++kk) {
            float4 w = *(const float4*)&sw[(k0 + kk) * 128 + fq * 4];
#pragma unroll
            for (int i = 0; i < 8; ++i) {
                float xs = (kk == 0) ? xv[i].x : (kk == 1) ? xv[i].y
                         : (kk == 2) ? xv[i].z : xv[i].w;
                acc[i][0] = fmaf(xs, w.x, acc[i][0]);
                acc[i][1] = fmaf(xs, w.y, acc[i][1]);
                acc[i][2] = fmaf(xs, w.z, acc[i][2]);
                acc[i][3] = fmaf(xs, w.w, acc[i][3]);
            }
        }
    }

    int col = fq * 4;
    float* o = (col < 64) ? oa : ob;
    int c = col & 63;
#pragma unroll
    for (int i = 0; i < 8; ++i) {
        int n = base + nq * 8 + i;
        if (n < N)
            *(float4*)&o[(size_t)n * 64 + c] =
                make_float4(acc[i][0], acc[i][1], acc[i][2], acc[i][3]);
    }
}

// ---- CSR build ----
__global__ void k_deg(const int* __restrict__ dst, int* __restrict__ deg, int E) {
    int e = blockIdx.x * blockDim.x + threadIdx.x;
    if (e < E) atomicAdd(&deg[dst[e]], 1);
}

__global__ void k_scan1(const int* __restrict__ deg, int* __restrict__ spart,
                        int* __restrict__ bsum, int N) {
    __shared__ int sh[256];
    int base = blockIdx.x * 1024;
    int t = threadIdx.x;
    int v[4]; int sum = 0;
#pragma unroll
    for (int i = 0; i < 4; ++i) {
        int idx = base + t * 4 + i;
        v[i] = (idx < N) ? deg[idx] : 0;
        sum += v[i];
    }
    sh[t] = sum;
    __syncthreads();
    for (int off = 1; off < 256; off <<= 1) {
        int x = (t >= off) ? sh[t - off] : 0;
        __syncthreads();
        sh[t] += x;
        __syncthreads();
    }
    int run = (t > 0) ? sh[t - 1] : 0;
#pragma unroll
    for (int i = 0; i < 4; ++i) {
        run += v[i];
        int idx = base + t * 4 + i;
        if (idx < N) spart[idx] = run;
    }
    if (t == 255) bsum[blockIdx.x] = sh[255];
}

__global__ void k_scan2(int* __restrict__ bsum, int nb) {
    __shared__ int sh[128];
    int t = threadIdx.x;
    sh[t] = (t < nb) ? bsum[t] : 0;
    __syncthreads();
    for (int off = 1; off < 128; off <<= 1) {
        int x = (t >= off) ? sh[t - off] : 0;
        __syncthreads();
        sh[t] += x;
        __syncthreads();
    }
    if (t < nb) bsum[t] = (t > 0) ? sh[t - 1] : 0;
}

// scan3 + fused binit + fill-zeroing + pool-buffer zeroing.
__global__ void k_scan3(const int* __restrict__ spart, const int* __restrict__ bsum,
                        int* __restrict__ rowptr, int* __restrict__ fill,
                        int* __restrict__ bfill, float* __restrict__ pl0,
                        int shift, int B, int N) {
    int i = blockIdx.x * blockDim.x + threadIdx.x;
    if (i < N) {
        rowptr[i + 1] = spart[i] + bsum[i >> 10];
        fill[i] = 0;
    }
    if (i == 0) rowptr[0] = 0;
    if (i < B) {
        long long node = (long long)i << shift;
        if (node > N) node = N;
        bfill[i] = (node == 0) ? 0
                 : spart[node - 1] + bsum[(int)((node - 1) >> 10)];
    }
    if (i < 4096 + 64) pl0[i] = 0.f;   // pool[64,64] + cnt[64]
}

// Pass A: partition edges into dst-range buckets (bucket = dst>>shift).
// 8B staging record: {eid:24 | src:28 | dst_low:12}.
__global__ void k_part(const int* __restrict__ src, const int* __restrict__ dst,
                       int* __restrict__ bfill, unsigned long long* __restrict__ stg,
                       int shift, int E, int chunk) {
    __shared__ int hist[512];
    __shared__ int base[512];
    int t = threadIdx.x;
    int e0 = blockIdx.x * chunk;
    int e1 = e0 + chunk; if (e1 > E) e1 = E;
    for (int i = t; i < 512; i += 256) hist[i] = 0;
    __syncthreads();
    for (int e = e0 + t; e < e1; e += 256)
        atomicAdd(&hist[(unsigned)dst[e] >> shift], 1);
    __syncthreads();
    for (int i = t; i < 512; i += 256) {
        int h = hist[i];
        base[i] = h ? atomicAdd(&bfill[i], h) : 0;
    }
    __syncthreads();
    for (int i = t; i < 512; i += 256) hist[i] = 0;
    __syncthreads();
    unsigned mask = (1u << shift) - 1u;
    for (int e = e0 + t; e < e1; e += 256) {
        int d = dst[e];
        int b = (unsigned)d >> shift;
        int off = atomicAdd(&hist[b], 1);
        unsigned long long p = ((unsigned long long)(unsigned)e << 40)
                             | ((unsigned long long)(unsigned)src[e] << 12)
                             | (unsigned long long)((unsigned)d & mask);
        stg[(size_t)(base[b] + off)] = p;
    }
}

// Pass B: one block per bucket; scatter within the bucket's contiguous CSR
// range -> all of a line's writes come from ONE block/CU/L2. (Keep this as a
// SEPARATE launch: co-scheduling with streaming kernels evicts the partial
// CSR lines and resurrects the 64B/record write amplification — R17 lesson.)
__global__ void k_scat2(const unsigned long long* __restrict__ stg,
                        const int* __restrict__ rowptr, int* __restrict__ fill,
                        int2* __restrict__ csr, int shift, int N) {
    int b = blockIdx.x;
    long long n0 = (long long)b << shift; if (n0 > N) n0 = N;
    long long n1 = (long long)(b + 1) << shift; if (n1 > N) n1 = N;
    int s0 = rowptr[n0], s1 = rowptr[n1];
    unsigned mask = (1u << shift) - 1u;
    for (int i = s0 + (int)threadIdx.x; i < s1; i += 256) {
        unsigned long long p = stg[i];
        int dlow = (int)(p & mask);
        int s = (int)((p >> 12) & 0xFFFFFFFu);
        int eid = (int)(p >> 40);
        int d = (b << shift) | dlow;
        int pos = rowptr[d] + atomicAdd(&fill[d], 1);
        csr[pos] = make_int2(s, eid);
    }
}

// Single-pass scatter fallback.
__global__ void k_scatter(const int* __restrict__ src, const int* __restrict__ dst,
                          const int* __restrict__ rowptr, int* __restrict__ fill,
                          int2* __restrict__ csr, int E) {
    int e = blockIdx.x * blockDim.x + threadIdx.x;
    if (e >= E) return;
    int d = dst[e];
    int pos = rowptr[d] + atomicAdd(&fill[d], 1);
    csr[pos] = make_int2(src[e], e);
}

// Per-edge quad logit (log2 domain).
DEVINL float quad_logit(float4 a, float4 xv, float4 xr4,
                        float4 w0, float4 w1, float4 w2, float4 w3, float4 at) {
    float vx = fmaf(a.x, w0.x, fmaf(a.y, w1.x, fmaf(a.z, w2.x, fmaf(a.w, w3.x, xr4.x)))) + xv.x;
    float vy = fmaf(a.x, w0.y, fmaf(a.y, w1.y, fmaf(a.z, w2.y, fmaf(a.w, w3.y, xr4.y)))) + xv.y;
    float vz = fmaf(a.x, w0.z, fmaf(a.y, w1.z, fmaf(a.z, w2.z, fmaf(a.w, w3.z, xr4.z)))) + xv.z;
    float vw = fmaf(a.x, w0.w, fmaf(a.y, w1.w, fmaf(a.z, w2.w, fmaf(a.w, w3.w, xr4.w)))) + xv.w;
    vx = fmaxf(vx, 0.2f * vx);
    vy = fmaxf(vy, 0.2f * vy);
    vz = fmaxf(vz, 0.2f * vz);
    vw = fmaxf(vw, 0.2f * vw);
    float pv = fmaf(vx, at.x, fmaf(vy, at.y, fmaf(vz, at.z, vw * at.w)));
    return red4(pv);
}

// Fused GATv2 logits + segment-softmax + aggregation, node-parallel,
// EDGE-QUAD layout + deferred-max softmax + 2x unroll (8 edges in flight).
__global__ void k_gat_agg(const int* __restrict__ rowptr,
                          const int2* __restrict__ csr,   // {src, eid}
                          const float4* __restrict__ ea,  // [E] edge_attr
                          const float* __restrict__ xl,   // [N,64]
                          const float* __restrict__ xr,   // [N,64]
                          const float* __restrict__ We,   // [4,64]
                          const float* __restrict__ att,  // [64]
                          const float* __restrict__ bias, // [64]
                          float* __restrict__ out,        // [N,64]
                          int N, int elu) {
    int l = threadIdx.x & 63;
    int n = blockIdx.x * 4 + (threadIdx.x >> 6);
    if (n >= N) return;
    int q = l & 15;
    int g = l >> 4;
    int f4 = q * 4;
    const float LOG2E = 1.44269504088896f;

    float4 w0 = *(const float4*)&We[f4];
    float4 w1 = *(const float4*)&We[64 + f4];
    float4 w2 = *(const float4*)&We[128 + f4];
    float4 w3 = *(const float4*)&We[192 + f4];
    float4 at = *(const float4*)&att[f4];
    at.x *= LOG2E; at.y *= LOG2E; at.z *= LOG2E; at.w *= LOG2E;
    float4 xr4 = *(const float4*)&xr[(size_t)n * 64 + f4];

    int beg = rowptr[n], end = rowptr[n + 1];
    const float4* xl4 = (const float4*)xl;

    float m = -1e30f, den = 0.f;
    float4 acc = make_float4(0.f, 0.f, 0.f, 0.f);

    int jb = beg;
    for (; jb + 8 <= end; jb += 8) {
        int2 se0 = csr[jb + g];
        int2 se1 = csr[jb + 4 + g];
        float4 a0 = ea[(unsigned)se0.y];
        float4 a1 = ea[(unsigned)se1.y];
        float4 xv0 = xl4[(unsigned)se0.x * 16u + (unsigned)q];
        float4 xv1 = xl4[(unsigned)se1.x * 16u + (unsigned)q];
        float p0 = quad_logit(a0, xv0, xr4, w0, w1, w2, w3, at);
        float p1 = quad_logit(a1, xv1, xr4, w0, w1, w2, w3, at);
        if (__any(fmaxf(p0, p1) - m > 8.f)) {
            float mn = fmaxf(m, fmaxf(p0, p1));
            float sc = fexp2(m - mn);
            float e0 = fexp2(p0 - mn), e1 = fexp2(p1 - mn);
            den = fmaf(den, sc, e0 + e1);
            acc.x = fmaf(e0, xv0.x, fmaf(e1, xv1.x, acc.x * sc));
            acc.y = fmaf(e0, xv0.y, fmaf(e1, xv1.y, acc.y * sc));
            acc.z = fmaf(e0, xv0.z, fmaf(e1, xv1.z, acc.z * sc));
            acc.w = fmaf(e0, xv0.w, fmaf(e1, xv1.w, acc.w * sc));
            m = mn;
        } else {
            float e0 = fexp2(p0 - m), e1 = fexp2(p1 - m);
            den += e0 + e1;
            acc.x = fmaf(e0, xv0.x, fmaf(e1, xv1.x, acc.x));
            acc.y = fmaf(e0, xv0.y, fmaf(e1, xv1.y, acc.y));
            acc.z = fmaf(e0, xv0.z, fmaf(e1, xv1.z, acc.z));
            acc.w = fmaf(e0, xv0.w, fmaf(e1, xv1.w, acc.w));
        }
    }
    for (; jb < end; jb += 4) {
        int j = jb + g;
        bool valid = (j < end);
        int jj = valid ? j : end - 1;
        int2 se = csr[jj];
        float4 a = ea[(unsigned)se.y];
        float4 xv = xl4[(unsigned)se.x * 16u + (unsigned)q];
        float pv = quad_logit(a, xv, xr4, w0, w1, w2, w3, at);
        pv = valid ? pv : -3.0e38f;
        if (__any(pv - m > 8.f)) {
            float mn = fmaxf(m, pv);
            float sc = fexp2(m - mn);
            float e = fexp2(pv - mn);
            den = fmaf(den, sc, e);
            acc.x = fmaf(e, xv.x, acc.x * sc);
            acc.y = fmaf(e, xv.y, acc.y * sc);
            acc.z = fmaf(e, xv.z, acc.z * sc);
            acc.w = fmaf(e, xv.w, acc.w * sc);
            m = mn;
        } else {
            float e = fexp2(pv - m);
            den += e;
            acc.x = fmaf(e, xv.x, acc.x);
            acc.y = fmaf(e, xv.y, acc.y);
            acc.z = fmaf(e, xv.z, acc.z);
            acc.w = fmaf(e, xv.w, acc.w);
        }
    }

#pragma unroll
    for (int mask = 16; mask <= 32; mask <<= 1) {
        float m2 = __shfl_xor(m, mask);
        float d2 = __shfl_xor(den, mask);
        float ax = __shfl_xor(acc.x, mask);
        float ay = __shfl_xor(acc.y, mask);
        float az = __shfl_xor(acc.z, mask);
        float aw = __shfl_xor(acc.w, mask);
        float mn = fmaxf(m, m2);
        float s1 = fexp2(m - mn);
        float s2 = fexp2(m2 - mn);
        den = den * s1 + d2 * s2;
        acc.x = acc.x * s1 + ax * s2;
        acc.y = acc.y * s1 + ay * s2;
        acc.z = acc.z * s1 + az * s2;
        acc.w = acc.w * s1 + aw * s2;
        m = mn;
    }

    float inv = (den > 0.f) ? 1.f / den : 0.f;
    float4 b4 = *(const float4*)&bias[f4];
    float4 val;
    val.x = fmaf(acc.x, inv, b4.x);
    val.y = fmaf(acc.y, inv, b4.y);
    val.z = fmaf(acc.z, inv, b4.z);
    val.w = fmaf(acc.w, inv, b4.w);
    if (elu) {
        val.x = (val.x > 0.f) ? val.x : expm1f(val.x);
        val.y = (val.y > 0.f) ? val.y : expm1f(val.y);
        val.z = (val.z > 0.f) ? val.z : expm1f(val.z);
        val.w = (val.w > 0.f) ? val.w : expm1f(val.w);
    }
    if (l < 16) ((float4*)out)[(size_t)n * 16 + q] = val;
}

// Run-length accumulating pool.
__global__ void k_pool(const float* __restrict__ y2,
                       const int* __restrict__ batch,
                       float* __restrict__ pool, float* __restrict__ cnt, int N) {
    const int CH = 256;
    int f = threadIdx.x & 63;
    int lane = threadIdx.x >> 6;
    int base = blockIdx.x * CH;
    int curg = -1;
    float acc = 0.f;
    float c = 0.f;
    for (int n = base + lane; n < base + CH && n < N; n += 4) {
        int g = batch[n];
        if (g != curg) {
            if (curg >= 0) {
                atomicAdd(pool + (size_t)curg * 64 + f, acc);
                if (f == 0) atomicAdd(cnt + curg, c);
            }
            curg = g; acc = 0.f; c = 0.f;
        }
        acc += y2[(size_t)n * 64 + f];
        c += 1.f;
    }
    if (curg >= 0) {
        atomicAdd(pool + (size_t)curg * 64 + f, acc);
        if (f == 0) atomicAdd(cnt + curg, c);
    }
}

// One block (64 threads) per graph: mean, 3 MLP heads.
__global__ void k_head(const float* __restrict__ pool, const float* __restrict__ cnt,
                       const float* __restrict__ Wg1, const float* __restrict__ bg1,
                       const float* __restrict__ Wg2, const float* __restrict__ bg2,
                       const float* __restrict__ Wp, const float* __restrict__ bp,
                       const float* __restrict__ Wc1, const float* __restrict__ bc1,
                       const float* __restrict__ Wc2, const float* __restrict__ bc2,
                       float* __restrict__ out) {
    int g = blockIdx.x, f = threadIdx.x;
    __shared__ float sg[64];
    __shared__ float sh[64];
    float inv = 1.f / fmaxf(cnt[g], 1.f);
    sg[f] = pool[(size_t)g * 64 + f] * inv;
    __syncthreads();
    float acc = bg1[f];
    for (int k = 0; k < 64; ++k) acc += sg[k] * Wg1[k * 64 + f];
    sh[f] = fmaxf(acc, 0.f);
    __syncthreads();
    if (f < 15) {
        float o = bg2[f];
        for (int k = 0; k < 64; ++k) o += sh[k] * Wg2[k * 15 + f];
        out[(size_t)g * 15 + f] = o;
    }
    if (f < 10) {
        float o = bp[f];
        for (int k = 0; k < 64; ++k) o += sg[k] * Wp[k * 10 + f];
        out[960 + (size_t)g * 10 + f] = o;
    }
    __syncthreads();
    float acc2 = bc1[f];
    for (int k = 0; k < 64; ++k) acc2 += sg[k] * Wc1[k * 64 + f];
    sh[f] = fmaxf(acc2, 0.f);
    __syncthreads();
    if (f == 0) {
        float v = bc2[0];
        for (int k = 0; k < 64; ++k) v += sh[k] * Wc2[k];
        out[1600 + g] = v;
    }
}

extern "C" void kernel_launch(void* const* d_in, const int* in_sizes, int n_in,
                              void* d_out, int out_size, void* d_ws, size_t ws_size,
                              hipStream_t stream) {
    const float* x     = (const float*)d_in[0];
    const int*   ei    = (const int*)d_in[1];
    const float* ea    = (const float*)d_in[2];
    const int*   batch = (const int*)d_in[3];
    const float* Wl1 = (const float*)d_in[4];
    const float* Wr1 = (const float*)d_in[5];
    const float* We1 = (const float*)d_in[6];
    const float* att1 = (const float*)d_in[7];
    const float* b1  = (const float*)d_in[8];
    const float* Wl2 = (const float*)d_in[9];
    const float* Wr2 = (const float*)d_in[10];
    const float* We2 = (const float*)d_in[11];
    const float* att2 = (const float*)d_in[12];
    const float* b2  = (const float*)d_in[13];
    const float* Wg1 = (const float*)d_in[14];
    const float* bg1 = (const float*)d_in[15];
    const float* Wg2 = (const float*)d_in[16];
    const float* bg2 = (const float*)d_in[17];
    const float* Wp  = (const float*)d_in[18];
    const float* bp  = (const float*)d_in[19];
    const float* Wc1 = (const float*)d_in[20];
    const float* bc1 = (const float*)d_in[21];
    const float* Wc2 = (const float*)d_in[22];
    const float* bc2 = (const float*)d_in[23];

    const int N = in_sizes[0] / 16;       // 100000
    const int E = in_sizes[2] / 4;        // 1600000
    const int* src = ei;
    const int* dst = ei + E;

    // bucket shift: B = ceil(N >> shift) <= 512
    int shift = 8;
    while (((N + (1 << shift) - 1) >> shift) > 512) ++shift;
    int B = (N + (1 << shift) - 1) >> shift;
    // packing limits: dst_low <= 12 bits, src <= 28 bits, eid <= 24 bits
    bool radix = (shift <= 12) && (N <= (1 << 28)) && (E < (1 << 24));

    // workspace layout (bytes)
    size_t NF = (size_t)N * 64;
    char* w = (char*)d_ws;
    float* A  = (float*)w; w += NF * 4;
    float* B_ = (float*)w; w += NF * 4;
    float* C  = (float*)w; w += NF * 4;
    int2* csr = (int2*)w;  w += (size_t)E * 8;
    int* rowptr = (int*)w; w += (size_t)(N + 1) * 4;
    int* deg    = (int*)w; w += (size_t)N * 4;      // reused as fill
    int* spart  = (int*)w; w += (size_t)N * 4;
    int* bsum   = (int*)w; w += 128 * 4;
    int* bfill  = (int*)w; w += 513 * 4;
    float* PL   = (float*)w; w += 4096 * 4;
    float* CT   = (float*)w;
    // staging overlays C (E*8 = 12.8MB <= NF*4 = 25.6MB); C first written by agg1
    unsigned long long* stg = (unsigned long long*)C;
    radix = radix && ((size_t)E * 8 <= NF * 4);

    dim3 blk(256);
    int gE  = (E + 255) / 256;
    int gN  = (N + 255) / 256;
    int nb1 = (N + 1023) / 1024;
    int gAgg = (N + 3) / 4;
    int gLin = (N + 63) / 64;

    // ---- CSR build (shared by both layers) ----
    hipMemsetAsync(deg, 0, (size_t)N * sizeof(int), stream);
    k_deg<<<gE, blk, 0, stream>>>(dst, deg, E);
    k_scan1<<<nb1, blk, 0, stream>>>(deg, spart, bsum, N);
    k_scan2<<<1, 128, 0, stream>>>(bsum, nb1);
    // scan3 also zeroes `deg` (-> fill), computes bfill, zeroes pool+cnt
    k_scan3<<<gN, blk, 0, stream>>>(spart, bsum, rowptr, deg, bfill, PL,
                                    shift, B, N);
    if (radix) {
        int gridA = 512;
        int chunk = (E + gridA - 1) / gridA;
        k_part<<<gridA, blk, 0, stream>>>(src, dst, bfill, stg, shift, E, chunk);
        k_scat2<<<B, blk, 0, stream>>>(stg, rowptr, deg, csr, shift, N);
    } else {
        k_scatter<<<gE, blk, 0, stream>>>(src, dst, rowptr, deg, csr, E);
    }

    // ---- Layer 1 ---- (stg dead after scat2; agg1 overwrites C)
    k_lin_tiled<16><<<gLin, blk, 0, stream>>>(x, Wl1, Wr1, A, B_, N);
    k_gat_agg<<<gAgg, blk, 0, stream>>>(rowptr, csr, (const float4*)ea, A, B_,
                                        We1, att1, b1, C, N, 1);

    // ---- Layer 2 ---- (xl2 -> B_, xr2 -> A)
    k_lin_tiled<64><<<gLin, blk, 0, stream>>>(C, Wl2, Wr2, B_, A, N);
    k_gat_agg<<<gAgg, blk, 0, stream>>>(rowptr, csr, (const float4*)ea, B_, A,
                                        We2, att2, b2, C, N, 0);

    // ---- Pool + heads ----
    k_pool<<<(N + 255) / 256, blk, 0, stream>>>(C, batch, PL, CT, N);
    k_head<<<64, 64, 0, stream>>>(PL, CT, Wg1, bg1, Wg2, bg2, Wp, bp,
                                  Wc1, bc1, Wc2, bc2, (float*)d_out);
}